// Round 6
// baseline (301.773 us; speedup 1.0000x reference)
//
#include <hip/hip_runtime.h>
#include <math.h>

typedef __attribute__((ext_vector_type(8))) __bf16 bf16x8;
typedef __attribute__((ext_vector_type(8))) short short8;
typedef __attribute__((ext_vector_type(4))) float f32x4;
typedef unsigned int uint;
typedef unsigned short ushort;

// ---------------- helpers ----------------

__device__ inline bf16x8 ld_bf8(const ushort* p){
  short8 s = *reinterpret_cast<const short8*>(p);
  return __builtin_bit_cast(bf16x8, s);
}

__device__ inline ushort f2bf(float f){
  return __builtin_bit_cast(ushort, (__bf16)f);   // native RNE cast
}
__device__ inline uint pack2bf(float a, float b){
  return (uint)f2bf(a) | ((uint)f2bf(b) << 16);
}
__device__ inline float bf_lo(uint u){ return __builtin_bit_cast(float, u << 16); }
__device__ inline float bf_hi(uint u){ return __builtin_bit_cast(float, u & 0xFFFF0000u); }

// ---------------- CSR build ----------------

__global__ void k_hist(const int* __restrict__ dst, int* __restrict__ deg, int E){
  int e = blockIdx.x * blockDim.x + threadIdx.x;
  if (e < E) atomicAdd(&deg[dst[e]], 1);
}

__global__ __launch_bounds__(256) void k_scan_part(const int* __restrict__ deg, int* __restrict__ bsum, int N){
  int base = blockIdx.x * 1024 + threadIdx.x * 4;
  int s = 0;
  if (base + 3 < N){
    int4 v = *reinterpret_cast<const int4*>(deg + base);
    s = v.x + v.y + v.z + v.w;
  } else {
    for (int i = base; i < N && i < base + 4; ++i) s += deg[i];
  }
  #pragma unroll
  for (int o = 32; o; o >>= 1) s += __shfl_xor(s, o);
  __shared__ int sm[4];
  if ((threadIdx.x & 63) == 0) sm[threadIdx.x >> 6] = s;
  __syncthreads();
  if (threadIdx.x == 0) bsum[blockIdx.x] = sm[0] + sm[1] + sm[2] + sm[3];
}

__global__ __launch_bounds__(64) void k_scan_mid(int* __restrict__ bsum, int nb){
  int lane = threadIdx.x;
  int chunk = (nb + 63) >> 6;
  int b0 = lane * chunk;
  int b1 = b0 + chunk; if (b1 > nb) b1 = nb;
  int s = 0;
  for (int i = b0; i < b1; ++i) s += bsum[i];
  int incl = s;
  #pragma unroll
  for (int o = 1; o < 64; o <<= 1){
    int t = __shfl_up(incl, o);
    if (lane >= o) incl += t;
  }
  int run = incl - s;
  for (int i = b0; i < b1; ++i){
    int d = bsum[i];
    bsum[i] = run;
    run += d;
  }
}

__global__ __launch_bounds__(256) void k_scan_add(int* __restrict__ deg, int* __restrict__ offs,
                                                  const int* __restrict__ bsum, int N, int E){
  int base = blockIdx.x * 1024 + threadIdx.x * 4;
  int v0 = 0, v1 = 0, v2 = 0, v3 = 0;
  if (base + 3 < N){
    int4 v = *reinterpret_cast<const int4*>(deg + base);
    v0 = v.x; v1 = v.y; v2 = v.z; v3 = v.w;
  } else {
    if (base     < N) v0 = deg[base];
    if (base + 1 < N) v1 = deg[base + 1];
    if (base + 2 < N) v2 = deg[base + 2];
    if (base + 3 < N) v3 = deg[base + 3];
  }
  int s = v0 + v1 + v2 + v3;
  int lane = threadIdx.x & 63, wv = threadIdx.x >> 6;
  int incl = s;
  #pragma unroll
  for (int o = 1; o < 64; o <<= 1){
    int t = __shfl_up(incl, o);
    if (lane >= o) incl += t;
  }
  __shared__ int wsum[4];
  if (lane == 63) wsum[wv] = incl;
  __syncthreads();
  int woff = 0;
  for (int w = 0; w < wv; ++w) woff += wsum[w];
  int excl = bsum[blockIdx.x] + woff + incl - s;
  if (base     < N){ offs[base]     = excl; deg[base]     = excl; excl += v0; }
  if (base + 1 < N){ offs[base + 1] = excl; deg[base + 1] = excl; excl += v1; }
  if (base + 2 < N){ offs[base + 2] = excl; deg[base + 2] = excl; excl += v2; }
  if (base + 3 < N){ offs[base + 3] = excl; deg[base + 3] = excl; excl += v3; }
  if (blockIdx.x == 0 && threadIdx.x == 0) offs[N] = E;
}

__global__ void k_fill(const int* __restrict__ src, const int* __restrict__ dstv,
                       int* __restrict__ cursor, int* __restrict__ srclist, int E){
  int e = blockIdx.x * blockDim.x + threadIdx.x;
  if (e < E){
    int d = dstv[e];
    int pos = atomicAdd(&cursor[d], 1);
    srclist[pos] = src[e];
  }
}

// ---------------- casts ----------------

__global__ __launch_bounds__(256) void k_castv(const float* __restrict__ in, ushort* __restrict__ out, int n4){
  int i = blockIdx.x * blockDim.x + threadIdx.x;
  int stride = gridDim.x * blockDim.x;
  for (; i < n4; i += stride){
    const float4 v = reinterpret_cast<const float4*>(in)[i];
    uint2 o;
    o.x = pack2bf(v.x, v.y);
    o.y = pack2bf(v.z, v.w);
    reinterpret_cast<uint2*>(out)[i] = o;
  }
}

struct WSet { const float* src[12]; ushort* dst[12]; int n[12]; };

__global__ __launch_bounds__(256) void k_castw(WSet ws){
  int m = blockIdx.y;
  int n = ws.n[m];
  const float* s = ws.src[m];
  ushort* d = ws.dst[m];
  for (int i = blockIdx.x * blockDim.x + threadIdx.x; i < n; i += gridDim.x * blockDim.x)
    d[i] = f2bf(s[i]);
}

// ---------------- MFMA projections (swapped operand order) ----------------
// Block = 4 waves; wave w computes matrix w of {q,k,v,skip}.
// mfma(bf, af, acc): first operand lane index (W row n) = D "row" dim,
// second operand lane index (node row) = D "col" dim. So lane holds node
// row = lane&15 and 4 CONSECUTIVE output features n = (lane>>4)*4 + reg
// -> packed uint2 stores (bf16) / float4 stores (skip).

template<int KT, int NT>
__global__ __launch_bounds__(256) void k_projmfma(
    const ushort* __restrict__ hin, int N,
    const ushort* __restrict__ Wq, const ushort* __restrict__ Wk,
    const ushort* __restrict__ Wv, const ushort* __restrict__ Wsk,
    const float* __restrict__ bq, const float* __restrict__ bk,
    const float* __restrict__ bv, const float* __restrict__ bs,
    ushort* __restrict__ qo, ushort* __restrict__ ko, ushort* __restrict__ vo,
    int kvst, float* __restrict__ so)
{
  constexpr int K  = KT * 32;
  constexpr int FO = NT * 16;
  const int wv   = threadIdx.x >> 6;
  const int lane = threadIdx.x & 63;
  const int r16  = lane & 15;
  const int kg   = lane >> 4;

  const ushort* W = (wv == 0) ? Wq : (wv == 1) ? Wk : (wv == 2) ? Wv : Wsk;
  const float*  b = (wv == 0) ? bq : (wv == 1) ? bk : (wv == 2) ? bv : bs;

  bf16x8 bf[NT][KT];
  #pragma unroll
  for (int nt = 0; nt < NT; ++nt)
    #pragma unroll
    for (int kt = 0; kt < KT; ++kt)
      bf[nt][kt] = ld_bf8(W + (size_t)(nt * 16 + r16) * K + kt * 32 + kg * 8);

  float4 bias[NT];
  #pragma unroll
  for (int nt = 0; nt < NT; ++nt)
    bias[nt] = *reinterpret_cast<const float4*>(b + nt * 16 + kg * 4);

  const int MT = N >> 4;
  for (int mt = blockIdx.x; mt < MT; mt += gridDim.x){
    const int row0 = mt * 16;
    bf16x8 af[KT];
    #pragma unroll
    for (int kt = 0; kt < KT; ++kt)
      af[kt] = ld_bf8(hin + (size_t)(row0 + r16) * K + kt * 32 + kg * 8);

    f32x4 acc[NT];
    #pragma unroll
    for (int nt = 0; nt < NT; ++nt){
      acc[nt][0] = bias[nt].x; acc[nt][1] = bias[nt].y;
      acc[nt][2] = bias[nt].z; acc[nt][3] = bias[nt].w;
    }
    #pragma unroll
    for (int nt = 0; nt < NT; ++nt)
      #pragma unroll
      for (int kt = 0; kt < KT; ++kt)
        acc[nt] = __builtin_amdgcn_mfma_f32_16x16x32_bf16(bf[nt][kt], af[kt], acc[nt], 0, 0, 0);

    const int row = row0 + r16;
    if (wv < 3){
      ushort* out = (wv == 0) ? qo : (wv == 1) ? ko : vo;
      const int st = (wv == 0) ? FO : kvst;
      #pragma unroll
      for (int nt = 0; nt < NT; ++nt){
        uint* p = reinterpret_cast<uint*>(out + (size_t)row * st + nt * 16 + kg * 4);
        p[0] = pack2bf(acc[nt][0], acc[nt][1]);
        p[1] = pack2bf(acc[nt][2], acc[nt][3]);
      }
    } else {
      #pragma unroll
      for (int nt = 0; nt < NT; ++nt){
        float* p = so + (size_t)row * FO + nt * 16 + kg * 4;
        p[0] = acc[nt][0]; p[1] = acc[nt][1]; p[2] = acc[nt][2]; p[3] = acc[nt][3];
      }
    }
  }
}

// ---------------- attention: full-lane groups, batched edges ----------------
// G lanes per node (16 for FO=96 -> 6 feats/lane; 8 for FO=32 -> 4 feats/lane).
// All lanes active. 4 edges per iteration, next batch prefetched.
// MODE 0: out = bf16(relu(skip+agg)); MODE 1: out = fp32 log_softmax(skip+agg)

template<int FO, int G, int MODE>
__global__ __launch_bounds__(256) void k_attn2(
    const ushort* __restrict__ qb, const ushort* __restrict__ kv,
    const float* __restrict__ skip, const int* __restrict__ offs,
    const int* __restrict__ srclist, void* __restrict__ outp,
    int N, float scale)
{
  constexpr int FPL = FO / G;       // features per lane
  constexpr int WPL = FPL / 2;      // packed uint words per lane
  constexpr int KVW = 2 * FO;
  constexpr int GPW = 64 / G;
  const int lane = threadIdx.x & 63;
  const int sub  = lane & (G - 1);
  const int node = (blockIdx.x * (blockDim.x >> 6) + (threadIdx.x >> 6)) * GPW + lane / G;
  const bool nv  = node < N;
  const int nodec = nv ? node : 0;

  const uint* qrow = reinterpret_cast<const uint*>(qb + (size_t)nodec * FO + sub * FPL);
  float qf[FPL];
  #pragma unroll
  for (int w = 0; w < WPL; ++w){
    uint qw = qrow[w];
    qf[2 * w]     = bf_lo(qw);
    qf[2 * w + 1] = bf_hi(qw);
  }

  float m = -INFINITY, l = 0.f;
  float acc[FPL];
  #pragma unroll
  for (int f = 0; f < FPL; ++f) acc[f] = 0.f;

  int e0 = nv ? offs[node] : 0;
  int e1 = nv ? offs[node + 1] : 0;

  uint kk[4][WPL], vv[4][WPL];
  auto LOAD = [&](int eb, uint (*Kr)[WPL], uint (*Vr)[WPL]){
    #pragma unroll
    for (int i = 0; i < 4; ++i){
      int ee = eb + i;
      int ec = (ee < e1) ? ee : (e1 - 1);
      int j = srclist[ec];
      const uint* r = reinterpret_cast<const uint*>(kv + (size_t)j * KVW + sub * FPL);
      #pragma unroll
      for (int w = 0; w < WPL; ++w){
        Kr[i][w] = r[w];
        Vr[i][w] = r[FO / 2 + w];
      }
    }
  };

  if (e0 < e1){
    LOAD(e0, kk, vv);
    for (int e = e0; e < e1; ){
      const int en = e + 4;
      const bool more = en < e1;
      uint kn[4][WPL], vn[4][WPL];
      if (more) LOAD(en, kn, vn);

      float s[4];
      #pragma unroll
      for (int i = 0; i < 4; ++i){
        float t = 0.f;
        #pragma unroll
        for (int w = 0; w < WPL; ++w){
          t = fmaf(qf[2 * w],     bf_lo(kk[i][w]), t);
          t = fmaf(qf[2 * w + 1], bf_hi(kk[i][w]), t);
        }
        s[i] = t;
      }
      #pragma unroll
      for (int o = 1; o < G; o <<= 1){
        s[0] += __shfl_xor(s[0], o);
        s[1] += __shfl_xor(s[1], o);
        s[2] += __shfl_xor(s[2], o);
        s[3] += __shfl_xor(s[3], o);
      }
      s[0] = s[0] * scale;
      s[1] = (e + 1 < e1) ? s[1] * scale : -1e30f;
      s[2] = (e + 2 < e1) ? s[2] * scale : -1e30f;
      s[3] = (e + 3 < e1) ? s[3] * scale : -1e30f;

      float mnew = fmaxf(fmaxf(m, s[0]), fmaxf(fmaxf(s[1], s[2]), s[3]));
      float sfac = __expf(m - mnew);
      float p[4];
      p[0] = __expf(s[0] - mnew);
      p[1] = __expf(s[1] - mnew);
      p[2] = __expf(s[2] - mnew);
      p[3] = __expf(s[3] - mnew);
      l = l * sfac + (p[0] + p[1]) + (p[2] + p[3]);
      #pragma unroll
      for (int f = 0; f < FPL; ++f) acc[f] *= sfac;
      #pragma unroll
      for (int i = 0; i < 4; ++i)
        #pragma unroll
        for (int w = 0; w < WPL; ++w){
          acc[2 * w]     = fmaf(p[i], bf_lo(vv[i][w]), acc[2 * w]);
          acc[2 * w + 1] = fmaf(p[i], bf_hi(vv[i][w]), acc[2 * w + 1]);
        }
      m = mnew;
      e = en;
      if (more){
        #pragma unroll
        for (int i = 0; i < 4; ++i)
          #pragma unroll
          for (int w = 0; w < WPL; ++w){ kk[i][w] = kn[i][w]; vv[i][w] = vn[i][w]; }
      }
    }
  }

  float inv = 1.f / fmaxf(l, 1e-16f);
  const float* srow = skip + (size_t)nodec * FO + sub * FPL;
  float val[FPL];
  #pragma unroll
  for (int f = 0; f < FPL; ++f) val[f] = srow[f] + acc[f] * inv;

  if (MODE == 0){
    if (nv){
      uint* orow = reinterpret_cast<uint*>((ushort*)outp + (size_t)node * FO + sub * FPL);
      #pragma unroll
      for (int w = 0; w < WPL; ++w)
        orow[w] = pack2bf(fmaxf(val[2 * w], 0.f), fmaxf(val[2 * w + 1], 0.f));
    }
  } else {
    float mx = -INFINITY;
    #pragma unroll
    for (int f = 0; f < FPL; ++f) mx = fmaxf(mx, val[f]);
    #pragma unroll
    for (int o = 1; o < G; o <<= 1) mx = fmaxf(mx, __shfl_xor(mx, o));
    float ssum = 0.f;
    #pragma unroll
    for (int f = 0; f < FPL; ++f) ssum += __expf(val[f] - mx);
    #pragma unroll
    for (int o = 1; o < G; o <<= 1) ssum += __shfl_xor(ssum, o);
    float lg = __logf(ssum);
    if (nv){
      float* orow = (float*)outp + (size_t)node * FO + sub * FPL;
      #pragma unroll
      for (int f = 0; f < FPL; ++f) orow[f] = val[f] - mx - lg;
    }
  }
}

// ---------------- launch ----------------

extern "C" void kernel_launch(void* const* d_in, const int* in_sizes, int n_in,
                              void* d_out, int out_size, void* d_ws, size_t ws_size,
                              hipStream_t stream)
{
  const float* x  = (const float*)d_in[0];
  const int*   ei = (const int*)d_in[1];
  const int N = in_sizes[0] / 128;
  const int E = in_sizes[1] / 2;

  const float* W1[4]; const float* b1[4];
  const float* W2[4]; const float* b2[4];
  const float* W3[4]; const float* b3[4];
  for (int i = 0; i < 4; ++i){
    W1[i] = (const float*)d_in[2 + i];   b1[i] = (const float*)d_in[6 + i];
    W2[i] = (const float*)d_in[10 + i];  b2[i] = (const float*)d_in[14 + i];
    W3[i] = (const float*)d_in[18 + i];  b3[i] = (const float*)d_in[22 + i];
  }

  size_t off = 0;
  auto alloc = [&](size_t bytes) -> void* {
    void* p = (char*)d_ws + off;
    off = (off + bytes + 255) & ~(size_t)255;
    return p;
  };
  int* offs    = (int*)alloc(((size_t)N + 1) * 4);
  int* cursor  = (int*)alloc((size_t)N * 4);
  int* srclist = (int*)alloc((size_t)E * 4);
  int* bsum    = (int*)alloc(1024 * 4);
  ushort* qb = (ushort*)alloc((size_t)N * 96 * 2);
  ushort* kvb = (ushort*)alloc((size_t)N * 192 * 2);
  float*  hF = (float*)alloc((size_t)N * 96 * 4);
  ushort* hb = (ushort*)alloc((size_t)N * 128 * 2);
  ushort* wb = (ushort*)alloc((size_t)98304 * 2);

  ushort* Wb1[4]; ushort* Wb2[4]; ushort* Wb3[4];
  for (int i = 0; i < 4; ++i){
    Wb1[i] = wb + (size_t)i * 12288;
    Wb2[i] = wb + 49152 + (size_t)i * 9216;
    Wb3[i] = wb + 49152 + 36864 + (size_t)i * 3072;
  }

  WSet wset;
  for (int i = 0; i < 4; ++i){
    wset.src[i]     = W1[i]; wset.dst[i]     = Wb1[i]; wset.n[i]     = 12288;
    wset.src[4 + i] = W2[i]; wset.dst[4 + i] = Wb2[i]; wset.n[4 + i] = 9216;
    wset.src[8 + i] = W3[i]; wset.dst[8 + i] = Wb3[i]; wset.n[8 + i] = 3072;
  }
  k_castw<<<dim3(48, 12), dim3(256), 0, stream>>>(wset);

  // --- CSR of incoming edges ---
  const int nb = (N + 1023) / 1024;
  hipMemsetAsync(cursor, 0, (size_t)N * sizeof(int), stream);
  k_hist<<<dim3((E + 255) / 256), dim3(256), 0, stream>>>(ei + E, cursor, E);
  k_scan_part<<<dim3(nb), dim3(256), 0, stream>>>(cursor, bsum, N);
  k_scan_mid<<<dim3(1), dim3(64), 0, stream>>>(bsum, nb);
  k_scan_add<<<dim3(nb), dim3(256), 0, stream>>>(cursor, offs, bsum, N, E);
  k_fill<<<dim3((E + 255) / 256), dim3(256), 0, stream>>>(ei, ei + E, cursor, srclist, E);

  k_castv<<<dim3(2048), dim3(256), 0, stream>>>(x, hb, N * 128 / 4);

  float* outf = (float*)d_out;
  const float sc96 = 1.0f / sqrtf(96.f);
  const float sc32 = 1.0f / sqrtf(32.f);

  const int MT = N / 16;
  const int tpb = (MT + 1023) / 1024;
  const int gridP = (MT + tpb - 1) / tpb;

  // layer 1: K=128, FO=96
  k_projmfma<4, 6><<<dim3(gridP), dim3(256), 0, stream>>>(hb, N,
      Wb1[0], Wb1[1], Wb1[2], Wb1[3], b1[0], b1[1], b1[2], b1[3],
      qb, kvb, kvb + 96, 192, hF);
  k_attn2<96, 16, 0><<<dim3((N + 15) / 16), dim3(256), 0, stream>>>(qb, kvb, hF, offs, srclist, hb, N, sc96);

  // layer 2: K=96, FO=96
  k_projmfma<3, 6><<<dim3(gridP), dim3(256), 0, stream>>>(hb, N,
      Wb2[0], Wb2[1], Wb2[2], Wb2[3], b2[0], b2[1], b2[2], b2[3],
      qb, kvb, kvb + 96, 192, hF);
  k_attn2<96, 16, 0><<<dim3((N + 15) / 16), dim3(256), 0, stream>>>(qb, kvb, hF, offs, srclist, hb, N, sc96);

  // layer 3: K=96, FO=32 (+ fused log_softmax)
  k_projmfma<3, 2><<<dim3(gridP), dim3(256), 0, stream>>>(hb, N,
      Wb3[0], Wb3[1], Wb3[2], Wb3[3], b3[0], b3[1], b3[2], b3[3],
      qb, kvb, kvb + 32, 64, hF);
  k_attn2<32, 8, 1><<<dim3((N + 31) / 32), dim3(256), 0, stream>>>(qb, kvb, hF, offs, srclist, outf, N, sc32);
}